// Round 15
// baseline (118.131 us; speedup 1.0000x reference)
//
#include <hip/hip_runtime.h>
#include <hip/hip_bf16.h>

#define B_ 8
#define R_ 256
#define C_ 256
#define H_ 8
#define D_ 64

typedef __attribute__((ext_vector_type(8))) short s8v;
typedef __attribute__((ext_vector_type(4))) short s4v;
typedef __attribute__((ext_vector_type(4))) float f4v;

static __device__ __forceinline__ unsigned short f2b(float x) {
    __hip_bfloat16 h = __float2bfloat16(x);
    return *reinterpret_cast<unsigned short*>(&h);
}
static __device__ __forceinline__ float b2f(unsigned short u) {
    union { unsigned int i; float f; } c;
    c.i = (unsigned int)u << 16;
    return c.f;
}

// ---------------------------------------------------------------------------
// prep (fused): blocks <2048: f32->bf16 embeddings (+ block 0 builds the MLP
// MFMA A-fragments); blocks >=2048: coalesced 64x64 LDS-tiled transpose of the
// four 512x512 projection weights into (N,K) bf16.
// ---------------------------------------------------------------------------
__global__ __launch_bounds__(256) void prep(
    const float* __restrict__ re, const float* __restrict__ ce,
    const float* __restrict__ W1, const float* __restrict__ W2,
    const float* __restrict__ alpha,
    const float* __restrict__ Wq, const float* __restrict__ Wk,
    const float* __restrict__ Wv, const float* __restrict__ Wo,
    unsigned short* __restrict__ reb, unsigned short* __restrict__ ceb,
    unsigned short* __restrict__ w1af, unsigned short* __restrict__ w2af,
    unsigned short* __restrict__ wqt, unsigned short* __restrict__ wkt,
    unsigned short* __restrict__ wvt, unsigned short* __restrict__ wot)
{
    __shared__ unsigned short ldsT[64][68];
    if (blockIdx.x >= 2048) {
        const int bb = blockIdx.x - 2048;
        const int which = bb >> 6;
        const float* W = which == 0 ? Wq : which == 1 ? Wk : which == 2 ? Wv : Wo;
        unsigned short* WT = which == 0 ? wqt : which == 1 ? wkt : which == 2 ? wvt : wot;
        const int k0 = (bb & 7) * 64;
        const int n0 = ((bb >> 3) & 7) * 64;
        const int tt = threadIdx.x;
        const int rn = tt & 15;
        const int rk = tt >> 4;
        #pragma unroll
        for (int i = 0; i < 4; ++i) {
            const int kk = rk + 16 * i;
            const float4 v = *(const float4*)&W[(size_t)(k0 + kk) * 512 + n0 + rn * 4];
            ldsT[rn * 4 + 0][kk] = f2b(v.x);
            ldsT[rn * 4 + 1][kk] = f2b(v.y);
            ldsT[rn * 4 + 2][kk] = f2b(v.z);
            ldsT[rn * 4 + 3][kk] = f2b(v.w);
        }
        __syncthreads();
        #pragma unroll
        for (int i = 0; i < 4; ++i) {
            const int nn = rk + 16 * i;
            const s4v r = *(const s4v*)&ldsT[nn][rn * 4];
            *(s4v*)&WT[(size_t)(n0 + nn) * 512 + k0 + rn * 4] = r;
        }
        return;
    }

    const int t = blockIdx.x * 256 + threadIdx.x;   // 0 .. 524287
    {
        float2 v = *(const float2*)&re[(size_t)t * 2];
        reb[t * 2]     = f2b(v.x);
        reb[t * 2 + 1] = f2b(v.y);
        float2 w = *(const float2*)&ce[(size_t)t * 2];
        ceb[t * 2]     = f2b(w.x);
        ceb[t * 2 + 1] = f2b(w.y);
    }
    if (blockIdx.x == 0) {
        const int l = threadIdx.x;
        for (int q = 0; q < 16; ++q) {              // w1af: 4096 elems
            const int idx = l * 16 + q;
            const int kk = idx & 7, lane = (idx >> 3) & 63, n = idx >> 9;
            const int j = n * 16 + (lane & 15);
            const int s = 8 * (lane >> 4) + kk;
            float val = 0.f;
            if (s < 16) {
                val = W1[(2 * (s >> 1)) * 128 + j];
            } else if (s < 18) {
                for (int h = 0; h < 8; ++h)
                    val += alpha[h] * W1[(2 * h + 1) * 128 + j];
            }
            w1af[idx] = f2b(val);
        }
        for (int q = 0; q < 8; ++q) {               // w2af: 2048 elems
            const int idx = l * 8 + q;
            const int kk = idx & 7, lane = (idx >> 3) & 63, kc = idx >> 9;
            const int h = lane & 15, g = lane >> 4;
            const int phi = 16 * (2 * kc + (kk >> 2)) + 4 * g + (kk & 3);
            w2af[idx] = f2b(h < 8 ? W2[phi * 8 + h] : 0.f);
        }
    }
}

// ---------------------------------------------------------------------------
// QKV projection, bf16 in / bf16 out, distance-1 register prefetch.
// z=0: Q*0.125 -> (B,R,512);  z=1: K -> (B,H,C,D);  z=2: V^T -> (B,H,D,C)
// ---------------------------------------------------------------------------
__global__ __launch_bounds__(256) void gemm_qkv(
    const unsigned short* __restrict__ reb, const unsigned short* __restrict__ ceb,
    const unsigned short* __restrict__ wqt, const unsigned short* __restrict__ wkt,
    const unsigned short* __restrict__ wvt,
    unsigned short* __restrict__ Qb, unsigned short* __restrict__ Kb,
    unsigned short* __restrict__ VT)
{
    const int z = blockIdx.z;
    const unsigned short* A;
    const unsigned short* Bm;
    int Ar0, Br0;
    if (z == 0)      { A = reb; Bm = wqt; Ar0 = blockIdx.x * 64; Br0 = blockIdx.y * 64; }
    else if (z == 1) { A = ceb; Bm = wkt; Ar0 = blockIdx.x * 64; Br0 = blockIdx.y * 64; }
    else             { A = wvt; Bm = ceb; Ar0 = blockIdx.y * 64; Br0 = blockIdx.x * 64; }

    const int t = threadIdx.x, lane = t & 63, wave = t >> 6;
    const int row0 = Ar0 + (wave >> 1) * 32;
    const int col0 = Br0 + (wave & 1) * 32;
    const int lr = lane & 15, ko = (lane >> 4) * 8;

    const unsigned short* Ap0 = A + (size_t)(row0 + lr) * 512 + ko;
    const unsigned short* Ap1 = Ap0 + 16 * 512;
    const unsigned short* Bp0 = Bm + (size_t)(col0 + lr) * 512 + ko;
    const unsigned short* Bp1 = Bp0 + 16 * 512;

    f4v acc[2][2] = {};
    s8v a0 = *(const s8v*)Ap0;
    s8v a1 = *(const s8v*)Ap1;
    s8v b0 = *(const s8v*)Bp0;
    s8v b1 = *(const s8v*)Bp1;
    #pragma unroll
    for (int k0 = 0; k0 < 512; k0 += 32) {
        const s8v ca0 = a0, ca1 = a1, cb0 = b0, cb1 = b1;
        if (k0 + 32 < 512) {
            a0 = *(const s8v*)(Ap0 + k0 + 32);
            a1 = *(const s8v*)(Ap1 + k0 + 32);
            b0 = *(const s8v*)(Bp0 + k0 + 32);
            b1 = *(const s8v*)(Bp1 + k0 + 32);
        }
        acc[0][0] = __builtin_amdgcn_mfma_f32_16x16x32_bf16(ca0, cb0, acc[0][0], 0, 0, 0);
        acc[0][1] = __builtin_amdgcn_mfma_f32_16x16x32_bf16(ca0, cb1, acc[0][1], 0, 0, 0);
        acc[1][0] = __builtin_amdgcn_mfma_f32_16x16x32_bf16(ca1, cb0, acc[1][0], 0, 0, 0);
        acc[1][1] = __builtin_amdgcn_mfma_f32_16x16x32_bf16(ca1, cb1, acc[1][1], 0, 0, 0);
    }

    const float sc = (z == 0) ? 0.125f : 1.0f;   // fold 1/sqrt(D) into Q
    const int rbase = (lane >> 4) * 4;
    #pragma unroll
    for (int i = 0; i < 2; ++i)
        #pragma unroll
        for (int j = 0; j < 2; ++j)
            #pragma unroll
            for (int reg = 0; reg < 4; ++reg) {
                const int rowIdx = row0 + i * 16 + rbase + reg;
                const int colIdx = col0 + j * 16 + lr;
                const unsigned short v = f2b(acc[i][j][reg] * sc);
                if (z == 0) {
                    Qb[(size_t)rowIdx * 512 + colIdx] = v;
                } else if (z == 1) {
                    const int b = rowIdx >> 8, c = rowIdx & 255;
                    const int h = colIdx >> 6, d = colIdx & 63;
                    Kb[(((size_t)b * 8 + h) * 256 + c) * 64 + d] = v;
                } else {
                    const int h = rowIdx >> 6, d = rowIdx & 63;
                    const int b = colIdx >> 8, c = colIdx & 255;
                    VT[(((size_t)b * 8 + h) * 64 + d) * 256 + c] = v;
                }
            }
}

// ---------------------------------------------------------------------------
// Final projection: out = OH(bf16) @ WoT(bf16) -> f32 (2048 x 512).
// Tile 32x64, grid (64,8) = 512 blocks (2/CU); distance-1 prefetch.
// ---------------------------------------------------------------------------
__global__ __launch_bounds__(256) void gemm_out(
    const unsigned short* __restrict__ OHb, const unsigned short* __restrict__ wot,
    float* __restrict__ out)
{
    const int t = threadIdx.x, lane = t & 63, wave = t >> 6;
    const int row0 = blockIdx.x * 32 + (wave & 1) * 16;
    const int col0 = blockIdx.y * 64 + (wave >> 1) * 32;
    const int lr = lane & 15, ko = (lane >> 4) * 8;

    const unsigned short* Ap0 = OHb + (size_t)(row0 + lr) * 512 + ko;
    const unsigned short* Bp0 = wot + (size_t)(col0 + lr) * 512 + ko;
    const unsigned short* Bp1 = Bp0 + 16 * 512;

    f4v acc[2] = {};
    s8v a0 = *(const s8v*)Ap0;
    s8v b0 = *(const s8v*)Bp0;
    s8v b1 = *(const s8v*)Bp1;
    #pragma unroll
    for (int k0 = 0; k0 < 512; k0 += 32) {
        const s8v ca0 = a0, cb0 = b0, cb1 = b1;
        if (k0 + 32 < 512) {
            a0 = *(const s8v*)(Ap0 + k0 + 32);
            b0 = *(const s8v*)(Bp0 + k0 + 32);
            b1 = *(const s8v*)(Bp1 + k0 + 32);
        }
        acc[0] = __builtin_amdgcn_mfma_f32_16x16x32_bf16(ca0, cb0, acc[0], 0, 0, 0);
        acc[1] = __builtin_amdgcn_mfma_f32_16x16x32_bf16(ca0, cb1, acc[1], 0, 0, 0);
    }

    const int rbase = (lane >> 4) * 4;
    #pragma unroll
    for (int j = 0; j < 2; ++j)
        #pragma unroll
        for (int reg = 0; reg < 4; ++reg)
            out[(size_t)(row0 + rbase + reg) * 512 + col0 + j * 16 + lr] = acc[j][reg];
}

// ---------------------------------------------------------------------------
// Fused attention: one block per (b, 2 rows), 512 threads (8 waves).
// Grid 1024 -> 4 blocks/CU (thread-limited), 32 waves/CU. LDS 36.25 KB.
// A: QK^T MFMA -> dotb[r][c] slots (hi/lo bf16 per head)        [barrier]
// B1: read dot fragments to registers                            [barrier]
// B2: MLP MFMA -> logits written TRANSPOSED in-place:
//     plane r reinterpreted as [8h][256c] f32 (exactly 8 KB)     [barrier]
// C: masked softmax (wave w: r=w&1, h=w>>1 and w>>1+4) -> w_t3   [barrier]
// D: PV MFMA (operand-swapped) -> OHb
// ---------------------------------------------------------------------------
__global__ __launch_bounds__(512, 4) void attn_fused(
    const unsigned short* __restrict__ Qb,   // (B,R,512) bf16, pre-scaled
    const unsigned short* __restrict__ Kb,   // (B,H,C,D) bf16
    const unsigned short* __restrict__ VT,   // (B,H,D,C) bf16
    const float* __restrict__ cost,          // (B,R,C) f32
    const int* __restrict__ mask,            // (B,R,C) int32
    const unsigned short* __restrict__ w1af, // [8][64][8] bf16
    const unsigned short* __restrict__ w2af, // [4][64][8] bf16
    unsigned short* __restrict__ OHb)        // (B,R,512) bf16
{
    __shared__ unsigned short dotb[2][256][16];  // 16 KB: dots -> logits(transposed)
    __shared__ unsigned short w_t3[8][2][264];   // 8.25 KB: weights [h][r][c+pad]
    __shared__ unsigned short ws1[4096];         // 8 KB: layer-1 A-frags
    __shared__ unsigned short ws2[2048];         // 4 KB: layer-2 A-frags

    const int t    = threadIdx.x;
    const int lane = t & 63;
    const int w    = t >> 6;          // wave 0..7
    const int li   = lane & 15;
    const int g    = lane >> 4;
    const int b    = blockIdx.y;
    const int r0   = blockIdx.x * 2;

    // stage MLP weight fragments into LDS (covered by phase-A barrier)
    ((s8v*)ws1)[t] = ((const s8v*)w1af)[t];
    if (t < 256) ((s8v*)ws2)[t] = ((const s8v*)w2af)[t];

    // register-prefetch phase-B cost values and phase-C mask values
    const int rB  = w & 1;            // phase-B and phase-C row for this wave
    const int ct0 = (w >> 1) * 4;     // 4 c-tiles per wave
    float costv[4];
    {
        const float* costRow = cost + ((size_t)b * R_ + r0 + rB) * 256;
        #pragma unroll
        for (int i = 0; i < 4; ++i)
            costv[i] = costRow[(ct0 + i) * 16 + li];
    }
    int mkp[4];
    {
        const int* maskRow = mask + ((size_t)b * R_ + r0 + rB) * 256;
        #pragma unroll
        for (int i = 0; i < 4; ++i)
            mkp[i] = maskRow[lane + 64 * i];
    }

    // ---- phase A: QK^T via MFMA; wave w owns head h=w, rows r0..r0+1 ----
    {
        const int rr = lane & 1;
        const int ko = g * 8;
        const unsigned short* Qp = Qb + ((size_t)b * R_ + r0 + rr) * 512 + w * 64 + ko;
        const s8v a0 = *(const s8v*)Qp;
        const s8v a1 = *(const s8v*)(Qp + 32);
        const unsigned short* Kp = Kb + (((size_t)b * 8 + w) * 256) * 64;
        #pragma unroll
        for (int ct = 0; ct < 16; ++ct) {
            const unsigned short* Bp = Kp + (size_t)(ct * 16 + li) * 64 + ko;
            const s8v b0 = *(const s8v*)Bp;
            const s8v b1v = *(const s8v*)(Bp + 32);
            f4v acc = __builtin_amdgcn_mfma_f32_16x16x32_bf16(a0, b0, (f4v){0.f,0.f,0.f,0.f}, 0, 0, 0);
            acc = __builtin_amdgcn_mfma_f32_16x16x32_bf16(a1, b1v, acc, 0, 0, 0);
            if (lane < 16) {
                const int c = ct * 16 + lane;
                #pragma unroll
                for (int reg = 0; reg < 2; ++reg) {    // rows 0,1 only
                    const float x = acc[reg];
                    const unsigned short hi = f2b(x);
                    const unsigned short lo = f2b(x - b2f(hi));
                    *(unsigned int*)&dotb[reg][c][2 * w] =
                        (unsigned int)hi | ((unsigned int)lo << 16);
                }
            }
        }
    }
    __syncthreads();

    // ---- phase B1: read dot fragments (before any logit overwrites) ----
    s8v b1r[4];
    #pragma unroll
    for (int i = 0; i < 4; ++i) {
        const int c = (ct0 + i) * 16 + li;
        b1r[i] = *(const s8v*)&dotb[rB][c][(g & 1) * 8];
    }
    __syncthreads();

    // ---- phase B2: MLP MFMA; logits written transposed in-place ----
    {
        float* lplane = (float*)&dotb[rB][0][0];   // [8h][256c] f32 view
        #pragma unroll
        for (int i = 0; i < 4; ++i) {
            const int c = (ct0 + i) * 16 + li;
            // B1 fragment: k 0..15 = interleaved hi/lo dots; 16,17 = cost hi/lo
            s8v b1;
            {
                const float cv = costv[i];
                const unsigned short chi = f2b(cv);
                const unsigned short clo = f2b(cv - b2f(chi));
                if (g < 2) {
                    b1 = b1r[i];
                } else if (g == 2) {
                    s8v bc = {0, 0, 0, 0, 0, 0, 0, 0};
                    bc[0] = (short)chi; bc[1] = (short)clo;
                    b1 = bc;
                } else {
                    s8v bz = {0, 0, 0, 0, 0, 0, 0, 0};
                    b1 = bz;
                }
            }
            // layer 1 + relu + pack (hidden unit phi = 16n + 4g + reg)
            unsigned int pk[16];
            #pragma unroll
            for (int n = 0; n < 8; ++n) {
                const s8v w1A = *(const s8v*)&ws1[(n * 64 + lane) * 8];
                f4v acc = __builtin_amdgcn_mfma_f32_16x16x32_bf16(
                    w1A, b1, (f4v){0.f,0.f,0.f,0.f}, 0, 0, 0);
                const float a0 = fmaxf(acc[0], 0.f), a1 = fmaxf(acc[1], 0.f);
                const float a2 = fmaxf(acc[2], 0.f), a3 = fmaxf(acc[3], 0.f);
                pk[2 * n]     = (unsigned int)f2b(a0) | ((unsigned int)f2b(a1) << 16);
                pk[2 * n + 1] = (unsigned int)f2b(a2) | ((unsigned int)f2b(a3) << 16);
            }
            // layer 2: b2 fragments are pure register re-aliasing (phi2 match)
            f4v acc2 = (f4v){0.f, 0.f, 0.f, 0.f};
            #pragma unroll
            for (int kc = 0; kc < 4; ++kc) {
                const s8v w2A = *(const s8v*)&ws2[(kc * 64 + lane) * 8];
                union { s8v v; unsigned int u[4]; } bb;
                bb.u[0] = pk[4 * kc + 0];
                bb.u[1] = pk[4 * kc + 1];
                bb.u[2] = pk[4 * kc + 2];
                bb.u[3] = pk[4 * kc + 3];
                acc2 = __builtin_amdgcn_mfma_f32_16x16x32_bf16(w2A, bb.v, acc2, 0, 0, 0);
            }
            // logits (h = 4g+reg, valid g<2) -> transposed [h][c] layout
            if (g < 2) {
                #pragma unroll
                for (int reg = 0; reg < 4; ++reg)
                    lplane[(4 * g + reg) * 256 + c] = acc2[reg];
            }
        }
    }
    __syncthreads();

    // ---- phase C: masked softmax; wave w: r=w&1, h = w>>1 and w>>1+4;
    //      logits read from transposed plane (2-way banks) ----
    {
        const float* lplane = (const float*)&dotb[rB][0][0];
        #pragma unroll
        for (int p = 0; p < 2; ++p) {
            const int h = (w >> 1) + p * 4;
            float v[4];
            #pragma unroll
            for (int i = 0; i < 4; ++i)
                v[i] = lplane[h * 256 + lane + 64 * i];
            #pragma unroll
            for (int i = 0; i < 4; ++i)
                v[i] = mkp[i] ? -INFINITY : v[i];
            float mx = fmaxf(fmaxf(v[0], v[1]), fmaxf(v[2], v[3]));
            #pragma unroll
            for (int off = 32; off >= 1; off >>= 1)
                mx = fmaxf(mx, __shfl_xor(mx, off));
            float e[4];
            #pragma unroll
            for (int i = 0; i < 4; ++i)
                e[i] = mkp[i] ? 0.f : __expf(v[i] - mx);
            float sm = e[0] + e[1] + e[2] + e[3];
            #pragma unroll
            for (int off = 32; off >= 1; off >>= 1)
                sm += __shfl_xor(sm, off);
            const float inv = sm > 0.f ? 1.0f / sm : 0.f;   // all-masked -> 0
            #pragma unroll
            for (int i = 0; i < 4; ++i)
                w_t3[h][rB][lane + 64 * i] = f2b(e[i] * inv);
        }
    }
    __syncthreads();

    // ---- phase D: PV via MFMA, operand-swapped (A=V^T, B=weights[h=w]);
    //      wave w owns head h=w. C/D: row=d offset, col=r (2 valid). ----
    {
        s8v bfr[8];
        #pragma unroll
        for (int kt = 0; kt < 8; ++kt)
            bfr[kt] = *(const s8v*)&w_t3[w][li & 1][kt * 32 + g * 8];
        const unsigned short* Vp = VT + (((size_t)b * 8 + w) * 64) * 256;
        #pragma unroll
        for (int dt = 0; dt < 4; ++dt) {
            const unsigned short* Ap = Vp + (size_t)(dt * 16 + li) * 256 + g * 8;
            f4v acc = (f4v){0.f, 0.f, 0.f, 0.f};
            #pragma unroll
            for (int kt = 0; kt < 8; ++kt)
                acc = __builtin_amdgcn_mfma_f32_16x16x32_bf16(
                    *(const s8v*)(Ap + kt * 32), bfr[kt], acc, 0, 0, 0);
            if (li < 2) {
                s4v o;
                o[0] = (short)f2b(acc[0]);
                o[1] = (short)f2b(acc[1]);
                o[2] = (short)f2b(acc[2]);
                o[3] = (short)f2b(acc[3]);
                *(s4v*)&OHb[((size_t)b * R_ + r0 + li) * 512 + w * 64 + dt * 16 + 4 * g] = o;
            }
        }
    }
}

// ---------------------------------------------------------------------------
extern "C" void kernel_launch(void* const* d_in, const int* in_sizes, int n_in,
                              void* d_out, int out_size, void* d_ws, size_t ws_size,
                              hipStream_t stream)
{
    const float* row_emb = (const float*)d_in[0];
    const float* col_emb = (const float*)d_in[1];
    const float* cost    = (const float*)d_in[2];
    const int*   mask    = (const int*)d_in[3];
    const float* Wq = (const float*)d_in[4];
    const float* Wk = (const float*)d_in[5];
    const float* Wv = (const float*)d_in[6];
    const float* Wo = (const float*)d_in[7];
    const float* W1 = (const float*)d_in[8];
    const float* W2 = (const float*)d_in[9];
    const float* alpha = (const float*)d_in[10];
    float* out = (float*)d_out;

    unsigned short* base = (unsigned short*)d_ws;
    unsigned short* Qb   = base;             // 1,048,576 shorts (B,R,512)
    unsigned short* Kb   = base + 1048576;   // (B,H,C,D)
    unsigned short* VT   = base + 2097152;   // (B,H,D,C)
    unsigned short* OHb  = base + 3145728;   // (B,R,512)
    unsigned short* reb  = base + 4194304;   // (B,R,512)
    unsigned short* ceb  = base + 5242880;   // (B,C,512)
    unsigned short* wqt  = base + 6291456;   // 262,144 each (512x512 N,K)
    unsigned short* wkt  = base + 6553600;
    unsigned short* wvt  = base + 6815744;
    unsigned short* wot  = base + 7077888;
    unsigned short* w1af = base + 7340032;   // 4096
    unsigned short* w2af = base + 7344128;   // 2048 -> end 7,346,176 (~14.7 MB)

    prep<<<2304, 256, 0, stream>>>(row_emb, col_emb, W1, W2, alpha,
                                   Wq, Wk, Wv, Wo,
                                   reb, ceb, w1af, w2af, wqt, wkt, wvt, wot);
    gemm_qkv<<<dim3(32, 8, 3), 256, 0, stream>>>(reb, ceb, wqt, wkt, wvt,
                                                 Qb, Kb, VT);
    attn_fused<<<dim3(128, 8), 512, 0, stream>>>(Qb, Kb, VT, cost, mask,
                                                 w1af, w2af, OHb);
    gemm_out<<<dim3(64, 8), 256, 0, stream>>>(OHb, wot, out);
}

// Round 16
// 83.376 us; speedup vs baseline: 1.4168x; 1.4168x over previous
//
#include <hip/hip_runtime.h>
#include <hip/hip_bf16.h>

#define B_ 8
#define R_ 256
#define C_ 256
#define H_ 8
#define D_ 64

typedef __attribute__((ext_vector_type(8))) short s8v;
typedef __attribute__((ext_vector_type(4))) short s4v;
typedef __attribute__((ext_vector_type(4))) float f4v;

static __device__ __forceinline__ unsigned short f2b(float x) {
    __hip_bfloat16 h = __float2bfloat16(x);
    return *reinterpret_cast<unsigned short*>(&h);
}
static __device__ __forceinline__ float b2f(unsigned short u) {
    union { unsigned int i; float f; } c;
    c.i = (unsigned int)u << 16;
    return c.f;
}

// ---------------------------------------------------------------------------
// prep (fused): blocks <2048: f32->bf16 embeddings (+ block 0 builds the MLP
// MFMA A-fragments); blocks >=2048: coalesced 64x64 LDS-tiled transpose of the
// four 512x512 projection weights into (N,K) bf16.
// ---------------------------------------------------------------------------
__global__ __launch_bounds__(256) void prep(
    const float* __restrict__ re, const float* __restrict__ ce,
    const float* __restrict__ W1, const float* __restrict__ W2,
    const float* __restrict__ alpha,
    const float* __restrict__ Wq, const float* __restrict__ Wk,
    const float* __restrict__ Wv, const float* __restrict__ Wo,
    unsigned short* __restrict__ reb, unsigned short* __restrict__ ceb,
    unsigned short* __restrict__ w1af, unsigned short* __restrict__ w2af,
    unsigned short* __restrict__ wqt, unsigned short* __restrict__ wkt,
    unsigned short* __restrict__ wvt, unsigned short* __restrict__ wot)
{
    __shared__ unsigned short ldsT[64][68];
    if (blockIdx.x >= 2048) {
        const int bb = blockIdx.x - 2048;
        const int which = bb >> 6;
        const float* W = which == 0 ? Wq : which == 1 ? Wk : which == 2 ? Wv : Wo;
        unsigned short* WT = which == 0 ? wqt : which == 1 ? wkt : which == 2 ? wvt : wot;
        const int k0 = (bb & 7) * 64;
        const int n0 = ((bb >> 3) & 7) * 64;
        const int tt = threadIdx.x;
        const int rn = tt & 15;
        const int rk = tt >> 4;
        #pragma unroll
        for (int i = 0; i < 4; ++i) {
            const int kk = rk + 16 * i;
            const float4 v = *(const float4*)&W[(size_t)(k0 + kk) * 512 + n0 + rn * 4];
            ldsT[rn * 4 + 0][kk] = f2b(v.x);
            ldsT[rn * 4 + 1][kk] = f2b(v.y);
            ldsT[rn * 4 + 2][kk] = f2b(v.z);
            ldsT[rn * 4 + 3][kk] = f2b(v.w);
        }
        __syncthreads();
        #pragma unroll
        for (int i = 0; i < 4; ++i) {
            const int nn = rk + 16 * i;
            const s4v r = *(const s4v*)&ldsT[nn][rn * 4];
            *(s4v*)&WT[(size_t)(n0 + nn) * 512 + k0 + rn * 4] = r;
        }
        return;
    }

    const int t = blockIdx.x * 256 + threadIdx.x;   // 0 .. 524287
    {
        float2 v = *(const float2*)&re[(size_t)t * 2];
        reb[t * 2]     = f2b(v.x);
        reb[t * 2 + 1] = f2b(v.y);
        float2 w = *(const float2*)&ce[(size_t)t * 2];
        ceb[t * 2]     = f2b(w.x);
        ceb[t * 2 + 1] = f2b(w.y);
    }
    if (blockIdx.x == 0) {
        const int l = threadIdx.x;
        for (int q = 0; q < 16; ++q) {              // w1af: 4096 elems
            const int idx = l * 16 + q;
            const int kk = idx & 7, lane = (idx >> 3) & 63, n = idx >> 9;
            const int j = n * 16 + (lane & 15);
            const int s = 8 * (lane >> 4) + kk;
            float val = 0.f;
            if (s < 16) {
                val = W1[(2 * (s >> 1)) * 128 + j];
            } else if (s < 18) {
                for (int h = 0; h < 8; ++h)
                    val += alpha[h] * W1[(2 * h + 1) * 128 + j];
            }
            w1af[idx] = f2b(val);
        }
        for (int q = 0; q < 8; ++q) {               // w2af: 2048 elems
            const int idx = l * 8 + q;
            const int kk = idx & 7, lane = (idx >> 3) & 63, kc = idx >> 9;
            const int h = lane & 15, g = lane >> 4;
            const int phi = 16 * (2 * kc + (kk >> 2)) + 4 * g + (kk & 3);
            w2af[idx] = f2b(h < 8 ? W2[phi * 8 + h] : 0.f);
        }
    }
}

// ---------------------------------------------------------------------------
// QKV projection, bf16 in / bf16 out, distance-1 register prefetch.
// z=0: Q*0.125 -> (B,R,512);  z=1: K -> (B,H,C,D);  z=2: V^T -> (B,H,D,C)
// ---------------------------------------------------------------------------
__global__ __launch_bounds__(256) void gemm_qkv(
    const unsigned short* __restrict__ reb, const unsigned short* __restrict__ ceb,
    const unsigned short* __restrict__ wqt, const unsigned short* __restrict__ wkt,
    const unsigned short* __restrict__ wvt,
    unsigned short* __restrict__ Qb, unsigned short* __restrict__ Kb,
    unsigned short* __restrict__ VT)
{
    const int z = blockIdx.z;
    const unsigned short* A;
    const unsigned short* Bm;
    int Ar0, Br0;
    if (z == 0)      { A = reb; Bm = wqt; Ar0 = blockIdx.x * 64; Br0 = blockIdx.y * 64; }
    else if (z == 1) { A = ceb; Bm = wkt; Ar0 = blockIdx.x * 64; Br0 = blockIdx.y * 64; }
    else             { A = wvt; Bm = ceb; Ar0 = blockIdx.y * 64; Br0 = blockIdx.x * 64; }

    const int t = threadIdx.x, lane = t & 63, wave = t >> 6;
    const int row0 = Ar0 + (wave >> 1) * 32;
    const int col0 = Br0 + (wave & 1) * 32;
    const int lr = lane & 15, ko = (lane >> 4) * 8;

    const unsigned short* Ap0 = A + (size_t)(row0 + lr) * 512 + ko;
    const unsigned short* Ap1 = Ap0 + 16 * 512;
    const unsigned short* Bp0 = Bm + (size_t)(col0 + lr) * 512 + ko;
    const unsigned short* Bp1 = Bp0 + 16 * 512;

    f4v acc[2][2] = {};
    s8v a0 = *(const s8v*)Ap0;
    s8v a1 = *(const s8v*)Ap1;
    s8v b0 = *(const s8v*)Bp0;
    s8v b1 = *(const s8v*)Bp1;
    #pragma unroll
    for (int k0 = 0; k0 < 512; k0 += 32) {
        const s8v ca0 = a0, ca1 = a1, cb0 = b0, cb1 = b1;
        if (k0 + 32 < 512) {
            a0 = *(const s8v*)(Ap0 + k0 + 32);
            a1 = *(const s8v*)(Ap1 + k0 + 32);
            b0 = *(const s8v*)(Bp0 + k0 + 32);
            b1 = *(const s8v*)(Bp1 + k0 + 32);
        }
        acc[0][0] = __builtin_amdgcn_mfma_f32_16x16x32_bf16(ca0, cb0, acc[0][0], 0, 0, 0);
        acc[0][1] = __builtin_amdgcn_mfma_f32_16x16x32_bf16(ca0, cb1, acc[0][1], 0, 0, 0);
        acc[1][0] = __builtin_amdgcn_mfma_f32_16x16x32_bf16(ca1, cb0, acc[1][0], 0, 0, 0);
        acc[1][1] = __builtin_amdgcn_mfma_f32_16x16x32_bf16(ca1, cb1, acc[1][1], 0, 0, 0);
    }

    const float sc = (z == 0) ? 0.125f : 1.0f;   // fold 1/sqrt(D) into Q
    const int rbase = (lane >> 4) * 4;
    #pragma unroll
    for (int i = 0; i < 2; ++i)
        #pragma unroll
        for (int j = 0; j < 2; ++j)
            #pragma unroll
            for (int reg = 0; reg < 4; ++reg) {
                const int rowIdx = row0 + i * 16 + rbase + reg;
                const int colIdx = col0 + j * 16 + lr;
                const unsigned short v = f2b(acc[i][j][reg] * sc);
                if (z == 0) {
                    Qb[(size_t)rowIdx * 512 + colIdx] = v;
                } else if (z == 1) {
                    const int b = rowIdx >> 8, c = rowIdx & 255;
                    const int h = colIdx >> 6, d = colIdx & 63;
                    Kb[(((size_t)b * 8 + h) * 256 + c) * 64 + d] = v;
                } else {
                    const int h = rowIdx >> 6, d = rowIdx & 63;
                    const int b = colIdx >> 8, c = colIdx & 255;
                    VT[(((size_t)b * 8 + h) * 64 + d) * 256 + c] = v;
                }
            }
}

// ---------------------------------------------------------------------------
// Final projection: out = OH(bf16) @ WoT(bf16) -> f32 (2048 x 512).
// Tile 32x64, grid (64,8) = 512 blocks (2/CU); distance-1 prefetch.
// ---------------------------------------------------------------------------
__global__ __launch_bounds__(256) void gemm_out(
    const unsigned short* __restrict__ OHb, const unsigned short* __restrict__ wot,
    float* __restrict__ out)
{
    const int t = threadIdx.x, lane = t & 63, wave = t >> 6;
    const int row0 = blockIdx.x * 32 + (wave & 1) * 16;
    const int col0 = blockIdx.y * 64 + (wave >> 1) * 32;
    const int lr = lane & 15, ko = (lane >> 4) * 8;

    const unsigned short* Ap0 = OHb + (size_t)(row0 + lr) * 512 + ko;
    const unsigned short* Bp0 = wot + (size_t)(col0 + lr) * 512 + ko;
    const unsigned short* Bp1 = Bp0 + 16 * 512;

    f4v acc[2] = {};
    s8v a0 = *(const s8v*)Ap0;
    s8v b0 = *(const s8v*)Bp0;
    s8v b1 = *(const s8v*)Bp1;
    #pragma unroll
    for (int k0 = 0; k0 < 512; k0 += 32) {
        const s8v ca0 = a0, cb0 = b0, cb1 = b1;
        if (k0 + 32 < 512) {
            a0 = *(const s8v*)(Ap0 + k0 + 32);
            b0 = *(const s8v*)(Bp0 + k0 + 32);
            b1 = *(const s8v*)(Bp1 + k0 + 32);
        }
        acc[0] = __builtin_amdgcn_mfma_f32_16x16x32_bf16(ca0, cb0, acc[0], 0, 0, 0);
        acc[1] = __builtin_amdgcn_mfma_f32_16x16x32_bf16(ca0, cb1, acc[1], 0, 0, 0);
    }

    const int rbase = (lane >> 4) * 4;
    #pragma unroll
    for (int j = 0; j < 2; ++j)
        #pragma unroll
        for (int reg = 0; reg < 4; ++reg)
            out[(size_t)(row0 + rbase + reg) * 512 + col0 + j * 16 + lr] = acc[j][reg];
}

// ---------------------------------------------------------------------------
// Fused attention: one block per (b, 8 rows), 1024 threads (16 waves).
// Waves w and w+8 share head h=w&7, splitting c-tiles (A) and d-tiles (D):
// halves per-block phase-A/D MFMA work and K/V traffic vs 4-row blocks.
// Grid 256 = 1 block/CU, 16 waves/CU. LDS ~110 KB.
// A:  QK^T MFMA (A rows = lane&7, 2x replicated) -> dotb hi/lo   [barrier]
// B1: pre-read dot fragments                                      [barrier]
// B2: MLP MFMA -> logits transposed in-place ([8h][256c] planes)  [barrier]
// C:  masked softmax (wave w: 4 of 64 (r,h) rows) -> w_t3         [barrier]
// D:  PV MFMA (operand-swapped; 2 d-tiles per wave) -> OHb
// ---------------------------------------------------------------------------
__global__ __launch_bounds__(1024) void attn_fused(
    const unsigned short* __restrict__ Qb,   // (B,R,512) bf16, pre-scaled
    const unsigned short* __restrict__ Kb,   // (B,H,C,D) bf16
    const unsigned short* __restrict__ VT,   // (B,H,D,C) bf16
    const float* __restrict__ cost,          // (B,R,C) f32
    const int* __restrict__ mask,            // (B,R,C) int32
    const unsigned short* __restrict__ w1af, // [8][64][8] bf16
    const unsigned short* __restrict__ w2af, // [4][64][8] bf16
    unsigned short* __restrict__ OHb)        // (B,R,512) bf16
{
    __shared__ unsigned short dotb[8][256][16];  // 64 KB: dots -> logits(transposed)
    __shared__ unsigned short w_t3[8][8][264];   // 33 KB: weights [h][r][c+pad]
    __shared__ unsigned short ws1[4096];         // 8 KB: layer-1 A-frags
    __shared__ unsigned short ws2[2048];         // 4 KB: layer-2 A-frags

    const int t    = threadIdx.x;
    const int lane = t & 63;
    const int w    = t >> 6;          // wave 0..15
    const int li   = lane & 15;
    const int g    = lane >> 4;
    const int b    = blockIdx.y;
    const int r0   = blockIdx.x * 8;

    const int h  = w & 7;             // head for phases A and D
    const int hf = w >> 3;            // half index (0/1)

    // stage MLP weight fragments into LDS (covered by phase-A barrier)
    if (t < 512) ((s8v*)ws1)[t] = ((const s8v*)w1af)[t];
    else if (t < 768) ((s8v*)ws2)[t - 512] = ((const s8v*)w2af)[t - 512];

    // phase-B assignment + cost prefetch: wave w -> row rB, 8 c-tiles
    const int rB  = w & 7;
    const int ct0 = hf * 8;
    float costv[8];
    {
        const float* costRow = cost + ((size_t)b * R_ + r0 + rB) * 256;
        #pragma unroll
        for (int i = 0; i < 8; ++i)
            costv[i] = costRow[(ct0 + i) * 16 + li];
    }
    // phase-C mask prefetch: wave w handles (r,h) rows idx = w*4 .. w*4+3
    int mkp[4][4];
    #pragma unroll
    for (int p = 0; p < 4; ++p) {
        const int idx = w * 4 + p;
        const int* maskRow = mask + ((size_t)b * R_ + r0 + (idx >> 3)) * 256;
        #pragma unroll
        for (int i = 0; i < 4; ++i)
            mkp[p][i] = maskRow[lane + 64 * i];
    }

    // ---- phase A: QK^T via MFMA; waves w,w+8 split head h's 16 c-tiles ----
    {
        const int rr = lane & 7;
        const int ko = g * 8;
        const unsigned short* Qp = Qb + ((size_t)b * R_ + r0 + rr) * 512 + h * 64 + ko;
        const s8v a0 = *(const s8v*)Qp;
        const s8v a1 = *(const s8v*)(Qp + 32);
        const unsigned short* Kp = Kb + (((size_t)b * 8 + h) * 256) * 64;
        #pragma unroll
        for (int c8 = 0; c8 < 8; ++c8) {
            const int ct = ct0 + c8;
            const unsigned short* Bp = Kp + (size_t)(ct * 16 + li) * 64 + ko;
            const s8v b0 = *(const s8v*)Bp;
            const s8v b1v = *(const s8v*)(Bp + 32);
            f4v acc = __builtin_amdgcn_mfma_f32_16x16x32_bf16(a0, b0, (f4v){0.f,0.f,0.f,0.f}, 0, 0, 0);
            acc = __builtin_amdgcn_mfma_f32_16x16x32_bf16(a1, b1v, acc, 0, 0, 0);
            if (g < 2) {
                const int c = ct * 16 + li;
                #pragma unroll
                for (int reg = 0; reg < 4; ++reg) {    // rows 4g+reg = 0..7
                    const float x = acc[reg];
                    const unsigned short hi = f2b(x);
                    const unsigned short lo = f2b(x - b2f(hi));
                    *(unsigned int*)&dotb[4 * g + reg][c][2 * h] =
                        (unsigned int)hi | ((unsigned int)lo << 16);
                }
            }
        }
    }
    __syncthreads();

    // ---- phase B1: read dot fragments (before any logit overwrites) ----
    s8v b1r[8];
    #pragma unroll
    for (int i = 0; i < 8; ++i) {
        const int c = (ct0 + i) * 16 + li;
        b1r[i] = *(const s8v*)&dotb[rB][c][(g & 1) * 8];
    }
    __syncthreads();

    // ---- phase B2: MLP MFMA; logits written transposed in-place ----
    {
        float* lplane = (float*)&dotb[rB][0][0];   // [8h][256c] f32 view
        #pragma unroll
        for (int i = 0; i < 8; ++i) {
            const int c = (ct0 + i) * 16 + li;
            // B1 fragment: k 0..15 = interleaved hi/lo dots; 16,17 = cost hi/lo
            s8v b1;
            {
                const float cv = costv[i];
                const unsigned short chi = f2b(cv);
                const unsigned short clo = f2b(cv - b2f(chi));
                if (g < 2) {
                    b1 = b1r[i];
                } else if (g == 2) {
                    s8v bc = {0, 0, 0, 0, 0, 0, 0, 0};
                    bc[0] = (short)chi; bc[1] = (short)clo;
                    b1 = bc;
                } else {
                    s8v bz = {0, 0, 0, 0, 0, 0, 0, 0};
                    b1 = bz;
                }
            }
            // layer 1 + relu + pack (hidden unit phi = 16n + 4g + reg)
            unsigned int pk[16];
            #pragma unroll
            for (int n = 0; n < 8; ++n) {
                const s8v w1A = *(const s8v*)&ws1[(n * 64 + lane) * 8];
                f4v acc = __builtin_amdgcn_mfma_f32_16x16x32_bf16(
                    w1A, b1, (f4v){0.f,0.f,0.f,0.f}, 0, 0, 0);
                const float a0 = fmaxf(acc[0], 0.f), a1 = fmaxf(acc[1], 0.f);
                const float a2 = fmaxf(acc[2], 0.f), a3 = fmaxf(acc[3], 0.f);
                pk[2 * n]     = (unsigned int)f2b(a0) | ((unsigned int)f2b(a1) << 16);
                pk[2 * n + 1] = (unsigned int)f2b(a2) | ((unsigned int)f2b(a3) << 16);
            }
            // layer 2: b2 fragments are pure register re-aliasing (phi2 match)
            f4v acc2 = (f4v){0.f, 0.f, 0.f, 0.f};
            #pragma unroll
            for (int kc = 0; kc < 4; ++kc) {
                const s8v w2A = *(const s8v*)&ws2[(kc * 64 + lane) * 8];
                union { s8v v; unsigned int u[4]; } bb;
                bb.u[0] = pk[4 * kc + 0];
                bb.u[1] = pk[4 * kc + 1];
                bb.u[2] = pk[4 * kc + 2];
                bb.u[3] = pk[4 * kc + 3];
                acc2 = __builtin_amdgcn_mfma_f32_16x16x32_bf16(w2A, bb.v, acc2, 0, 0, 0);
            }
            // logits (h' = 4g+reg, valid g<2) -> transposed [h'][c] layout
            if (g < 2) {
                #pragma unroll
                for (int reg = 0; reg < 4; ++reg)
                    lplane[(4 * g + reg) * 256 + c] = acc2[reg];
            }
        }
    }
    __syncthreads();

    // ---- phase C: masked softmax; wave w handles 4 of 64 (r,h') rows;
    //      logits read from transposed planes (conflict-free) ----
    {
        #pragma unroll
        for (int p = 0; p < 4; ++p) {
            const int idx = w * 4 + p;
            const int r = idx >> 3, hh = idx & 7;
            const float* lplane = (const float*)&dotb[r][0][0];
            float v[4];
            #pragma unroll
            for (int i = 0; i < 4; ++i)
                v[i] = lplane[hh * 256 + lane + 64 * i];
            #pragma unroll
            for (int i = 0; i < 4; ++i)
                v[i] = mkp[p][i] ? -INFINITY : v[i];
            float mx = fmaxf(fmaxf(v[0], v[1]), fmaxf(v[2], v[3]));
            #pragma unroll
            for (int off = 32; off >= 1; off >>= 1)
                mx = fmaxf(mx, __shfl_xor(mx, off));
            float e[4];
            #pragma unroll
            for (int i = 0; i < 4; ++i)
                e[i] = mkp[p][i] ? 0.f : __expf(v[i] - mx);
            float sm = e[0] + e[1] + e[2] + e[3];
            #pragma unroll
            for (int off = 32; off >= 1; off >>= 1)
                sm += __shfl_xor(sm, off);
            const float inv = sm > 0.f ? 1.0f / sm : 0.f;   // all-masked -> 0
            #pragma unroll
            for (int i = 0; i < 4; ++i)
                w_t3[hh][r][lane + 64 * i] = f2b(e[i] * inv);
        }
    }
    __syncthreads();

    // ---- phase D: PV via MFMA, operand-swapped (A=V^T, B=weights[h]);
    //      waves w,w+8 split head h's 4 d-tiles (2 each). C/D col=r (8 valid).
    {
        s8v bfr[8];
        #pragma unroll
        for (int kt = 0; kt < 8; ++kt)
            bfr[kt] = *(const s8v*)&w_t3[h][li & 7][kt * 32 + g * 8];
        const unsigned short* Vp = VT + (((size_t)b * 8 + h) * 64) * 256;
        #pragma unroll
        for (int d2 = 0; d2 < 2; ++d2) {
            const int dt = hf * 2 + d2;
            const unsigned short* Ap = Vp + (size_t)(dt * 16 + li) * 256 + g * 8;
            f4v acc = (f4v){0.f, 0.f, 0.f, 0.f};
            #pragma unroll
            for (int kt = 0; kt < 8; ++kt)
                acc = __builtin_amdgcn_mfma_f32_16x16x32_bf16(
                    *(const s8v*)(Ap + kt * 32), bfr[kt], acc, 0, 0, 0);
            if (li < 8) {
                s4v o;
                o[0] = (short)f2b(acc[0]);
                o[1] = (short)f2b(acc[1]);
                o[2] = (short)f2b(acc[2]);
                o[3] = (short)f2b(acc[3]);
                *(s4v*)&OHb[((size_t)b * R_ + r0 + li) * 512 + h * 64 + dt * 16 + 4 * g] = o;
            }
        }
    }
}

// ---------------------------------------------------------------------------
extern "C" void kernel_launch(void* const* d_in, const int* in_sizes, int n_in,
                              void* d_out, int out_size, void* d_ws, size_t ws_size,
                              hipStream_t stream)
{
    const float* row_emb = (const float*)d_in[0];
    const float* col_emb = (const float*)d_in[1];
    const float* cost    = (const float*)d_in[2];
    const int*   mask    = (const int*)d_in[3];
    const float* Wq = (const float*)d_in[4];
    const float* Wk = (const float*)d_in[5];
    const float* Wv = (const float*)d_in[6];
    const float* Wo = (const float*)d_in[7];
    const float* W1 = (const float*)d_in[8];
    const float* W2 = (const float*)d_in[9];
    const float* alpha = (const float*)d_in[10];
    float* out = (float*)d_out;

    unsigned short* base = (unsigned short*)d_ws;
    unsigned short* Qb   = base;             // 1,048,576 shorts (B,R,512)
    unsigned short* Kb   = base + 1048576;   // (B,H,C,D)
    unsigned short* VT   = base + 2097152;   // (B,H,D,C)
    unsigned short* OHb  = base + 3145728;   // (B,R,512)
    unsigned short* reb  = base + 4194304;   // (B,R,512)
    unsigned short* ceb  = base + 5242880;   // (B,C,512)
    unsigned short* wqt  = base + 6291456;   // 262,144 each (512x512 N,K)
    unsigned short* wkt  = base + 6553600;
    unsigned short* wvt  = base + 6815744;
    unsigned short* wot  = base + 7077888;
    unsigned short* w1af = base + 7340032;   // 4096
    unsigned short* w2af = base + 7344128;   // 2048 -> end 7,346,176 (~14.7 MB)

    prep<<<2304, 256, 0, stream>>>(row_emb, col_emb, W1, W2, alpha,
                                   Wq, Wk, Wv, Wo,
                                   reb, ceb, w1af, w2af, wqt, wkt, wvt, wot);
    gemm_qkv<<<dim3(32, 8, 3), 256, 0, stream>>>(reb, ceb, wqt, wkt, wvt,
                                                 Qb, Kb, VT);
    attn_fused<<<dim3(32, 8), 1024, 0, stream>>>(Qb, Kb, VT, cost, mask,
                                                 w1af, w2af, OHb);
    gemm_out<<<dim3(64, 8), 256, 0, stream>>>(OHb, wot, out);
}